// Round 3
// baseline (138.585 us; speedup 1.0000x reference)
//
#include <hip/hip_runtime.h>

// Updater: B=4194304 sequential scan, 3 independent scalar recurrences
//   net' = sigmoid(10*(net + u - 0.5)), u = W*x + b, pred = x . net'
// Chunked-scan parallelization with certified warm-up:
//   map is monotone in net -> trajectories from 0 and 1 bracket the truth.
//   WARM=16 dual-trajectory warm-up, wave-uniform early exit to single-traj,
//   geometric global-memory backoff (rare) terminating at exact net0.
// No LDS / no barrier: global float4 reads overlap compute (warm region of
// thread t == main region of thread t-1 -> L1/L2 serves re-reads).

#if __has_builtin(__builtin_amdgcn_exp2f)
#define EXP2F(v) __builtin_amdgcn_exp2f(v)
#else
#define EXP2F(v) __expf(0.6931471805599453f * (v))
#endif

namespace {
constexpr int   BTOT  = 4194304;
constexpr int   CHUNK = 16;                 // output steps per thread
constexpr int   BLOCK = 256;
constexpr int   WARM  = 16;                 // first-attempt warm-up length
constexpr int   NTHR  = BTOT / CHUNK;       // 262144
constexpr int   GRID  = NTHR / BLOCK;       // 1024 -> 4 blocks/CU, all resident
constexpr float KEXP  = -14.426950408889634f; // -10 * log2(e)
constexpr float EPS   = 1e-6f;
}

// sigmoid(10*(n+u-0.5)) = rcp(1 + exp2(KEXP*n + c)), c = (KEXP*W)x + KEXP*(b-.5)
#define CVALS(X0, X1, X2)                                                      \
  const float c0 = fmaf(kw00, (X0), fmaf(kw01, (X1), fmaf(kw02, (X2), kb0)));  \
  const float c1 = fmaf(kw10, (X0), fmaf(kw11, (X1), fmaf(kw12, (X2), kb1)));  \
  const float c2 = fmaf(kw20, (X0), fmaf(kw21, (X1), fmaf(kw22, (X2), kb2)));

#define SIG(N, C) __builtin_amdgcn_rcpf(1.0f + EXP2F(fmaf(KEXP, (N), (C))))

// dual-trajectory (bracket) step
#define US(X0, X1, X2)                                                         \
  do {                                                                         \
    CVALS(X0, X1, X2)                                                          \
    lo0 = SIG(lo0, c0); hi0 = SIG(hi0, c0);                                    \
    lo1 = SIG(lo1, c1); hi1 = SIG(hi1, c1);                                    \
    lo2 = SIG(lo2, c2); hi2 = SIG(hi2, c2);                                    \
  } while (0)

// single-trajectory step (no pred)
#define SS(X0, X1, X2)                                                         \
  do {                                                                         \
    CVALS(X0, X1, X2)                                                          \
    m0 = SIG(m0, c0); m1 = SIG(m1, c1); m2 = SIG(m2, c2);                      \
  } while (0)

// main step: advance + pred
#define MS(IDX, X0, X1, X2)                                                    \
  do {                                                                         \
    CVALS(X0, X1, X2)                                                          \
    m0 = SIG(m0, c0); m1 = SIG(m1, c1); m2 = SIG(m2, c2);                      \
    pr[(IDX)] = fmaf((X0), m0, fmaf((X1), m1, (X2) * m2));                     \
  } while (0)

// 4 steps from 3 packed float4 (dual / single / main variants)
#define US4(A, B4, C4)                                                         \
  do { US((A).x,(A).y,(A).z); US((A).w,(B4).x,(B4).y);                         \
       US((B4).z,(B4).w,(C4).x); US((C4).y,(C4).z,(C4).w); } while (0)
#define SS4(A, B4, C4)                                                         \
  do { SS((A).x,(A).y,(A).z); SS((A).w,(B4).x,(B4).y);                         \
       SS((B4).z,(B4).w,(C4).x); SS((C4).y,(C4).z,(C4).w); } while (0)
#define MS4(Q, A, B4, C4)                                                      \
  do { MS(4*(Q)+0,(A).x,(A).y,(A).z); MS(4*(Q)+1,(A).w,(B4).x,(B4).y);         \
       MS(4*(Q)+2,(B4).z,(B4).w,(C4).x); MS(4*(Q)+3,(C4).y,(C4).z,(C4).w); } while (0)

__global__ __launch_bounds__(BLOCK, 4) void Updater_65395172049297_kernel(
    const float* __restrict__ x, const float* __restrict__ W,
    const float* __restrict__ bv, const float* __restrict__ n0v,
    float* __restrict__ out)
{
    const int  tid   = blockIdx.x * BLOCK + threadIdx.x;
    const long start = (long)tid * CHUNK;

    // warm window: wl = min(start, WARM); start is a multiple of 16
    const int  wl    = (start < (long)WARM) ? (int)start : WARM;   // 0 or 16
    const bool exact = (start == (long)wl);    // warm-up reaches t=0 (tid 0,1)
    const int  gw    = wl >> 2;                // 0 or 4 groups

    // ---- issue loads early: warm window + first half of main chunk ----
    const float4* wp = reinterpret_cast<const float4*>(x + 3 * (start - wl));
    const float4* xp = reinterpret_cast<const float4*>(x + 3 * start);
    float4 wb[12];
    if (gw) {
#pragma unroll
        for (int i = 0; i < 12; ++i) wb[i] = wp[i];
    }
    float4 mb[12];
#pragma unroll
    for (int i = 0; i < 6; ++i) mb[i] = xp[i];

    const float kw00 = KEXP * W[0], kw01 = KEXP * W[1], kw02 = KEXP * W[2];
    const float kw10 = KEXP * W[3], kw11 = KEXP * W[4], kw12 = KEXP * W[5];
    const float kw20 = KEXP * W[6], kw21 = KEXP * W[7], kw22 = KEXP * W[8];
    const float kb0 = KEXP * (bv[0] - 0.5f);
    const float kb1 = KEXP * (bv[1] - 0.5f);
    const float kb2 = KEXP * (bv[2] - 0.5f);
    const float n00 = n0v[0], n01 = n0v[1], n02 = n0v[2];

    float lo0, lo1, lo2, hi0, hi1, hi2, m0, m1, m2;
    bool  conv = false;
    int   g    = 0;

    if (exact) {
        m0 = n00; m1 = n01; m2 = n02; conv = true;
    } else {
        lo0 = lo1 = lo2 = 0.0f; hi0 = hi1 = hi2 = 1.0f;
        for (; g < gw; ) {
            US4(wb[3*g], wb[3*g+1], wb[3*g+2]);
            ++g;
            conv = ((hi0 - lo0) < EPS) & ((hi1 - lo1) < EPS) & ((hi2 - lo2) < EPS);
            if (__all(conv)) break;
        }
        if (conv) { m0 = 0.5f*(lo0+hi0); m1 = 0.5f*(lo1+hi1); m2 = 0.5f*(lo2+hi2); }
    }

    if (conv) {
        // single-trajectory remainder of warm-up
        for (; g < gw; ++g) SS4(wb[3*g], wb[3*g+1], wb[3*g+2]);
    } else {
        // rare certified backoff: extend warm-up 4x per attempt (global reads)
        for (int a = 1; a < 12 && !conv; ++a) {
            long wl2 = (long)WARM << (2 * a);     // 64, 256, 1024, ...
            long bgn = start - wl2;
            bool ex2 = (bgn <= 0);
            if (ex2) bgn = 0;
            if (ex2) { lo0 = hi0 = n00; lo1 = hi1 = n01; lo2 = hi2 = n02; }
            else     { lo0 = lo1 = lo2 = 0.0f; hi0 = hi1 = hi2 = 1.0f; }
            for (long s2 = bgn; s2 < start; ++s2) {
                const float X0 = x[3*s2], X1 = x[3*s2+1], X2 = x[3*s2+2];
                US(X0, X1, X2);
            }
            conv = ex2 || (((hi0 - lo0) < EPS) & ((hi1 - lo1) < EPS) &
                           ((hi2 - lo2) < EPS));
        }
        m0 = 0.5f*(lo0+hi0); m1 = 0.5f*(lo1+hi1); m2 = 0.5f*(lo2+hi2);
    }

    // ---- issue second half of main loads, then compute 16 steps ----
#pragma unroll
    for (int i = 6; i < 12; ++i) mb[i] = xp[i];

    float pr[CHUNK];
    MS4(0, mb[0], mb[1],  mb[2]);
    MS4(1, mb[3], mb[4],  mb[5]);
    MS4(2, mb[6], mb[7],  mb[8]);
    MS4(3, mb[9], mb[10], mb[11]);

    float4* op = reinterpret_cast<float4*>(out + start);
#pragma unroll
    for (int i = 0; i < CHUNK / 4; ++i)
        op[i] = make_float4(pr[4*i+0], pr[4*i+1], pr[4*i+2], pr[4*i+3]);
}

extern "C" void kernel_launch(void* const* d_in, const int* in_sizes, int n_in,
                              void* d_out, int out_size, void* d_ws, size_t ws_size,
                              hipStream_t stream) {
    const float* x   = (const float*)d_in[0];   // (B,1,3)
    const float* W   = (const float*)d_in[1];   // (3,3)
    const float* bv  = (const float*)d_in[2];   // (3,)
    const float* n0v = (const float*)d_in[3];   // (3,1)
    float*       out = (float*)d_out;           // (B,1)
    Updater_65395172049297_kernel<<<GRID, BLOCK, 0, stream>>>(x, W, bv, n0v, out);
}